// Round 1
// baseline (1745.465 us; speedup 1.0000x reference)
//
#include <hip/hip_runtime.h>
#include <math.h>

#define N_OUT 32
#define D_OUT 32
#define N_IN 2048
#define D_IN 16
#define BATCH 64
#define J 1024           // N_OUT*D_OUT

#define BLOCK 512
#define NCHUNK 16        // n per block
#define BT 8             // b per thread
#define JT 8             // j per thread
// block covers 32 b (one half of batch) x all 1024 j

__device__ __forceinline__ int swz(int slot) { return slot ^ ((slot >> 3) & 7); }

template<bool HAS_V>
__global__ __launch_bounds__(BLOCK, 2)
void pass_kernel(const float* __restrict__ u, const float* __restrict__ W,
                 const float* __restrict__ vin, float* __restrict__ s_out)
{
  __shared__ float Wl[16 * 1024];   // stored at swizzled float4-slots
  __shared__ float uT[16][36];      // [i][b_local], padded to 36 (bank spread, 16B-aligned rows)
  __shared__ float al[32][32];      // logits -> softmax c, [b_local][o]

  const int t   = threadIdx.x;
  const int jg  = t & 127;          // j-group (8 j each)
  const int j0  = jg * JT;
  const int bg  = t >> 7;           // 0..3
  const int bl0 = bg * BT;          // local b base (0..31)
  const int b_base = blockIdx.y * 32;
  const int n0  = blockIdx.x * NCHUNK;
  const int o   = jg >> 2;          // this thread's output capsule (4 lanes share one o)

  // persistent v slice (pass >= 1)
  float vr[BT][JT];
  if (HAS_V) {
    #pragma unroll
    for (int bb = 0; bb < BT; ++bb) {
      const float4* vp = reinterpret_cast<const float4*>(vin + (size_t)(b_base + bl0 + bb) * J + j0);
      float4 a = vp[0], b4 = vp[1];
      vr[bb][0] = a.x;  vr[bb][1] = a.y;  vr[bb][2] = a.z;  vr[bb][3] = a.w;
      vr[bb][4] = b4.x; vr[bb][5] = b4.y; vr[bb][6] = b4.z; vr[bb][7] = b4.w;
    }
  }

  float acc[BT][JT];
  #pragma unroll
  for (int bb = 0; bb < BT; ++bb)
    #pragma unroll
    for (int q = 0; q < JT; ++q) acc[bb][q] = 0.f;

  for (int nn = 0; nn < NCHUNK; ++nn) {
    const int n = n0 + nn;

    // ---- stage W[n] (16 x 1024 f32 = 64KB), swizzled ----
    {
      const float4* Wg = reinterpret_cast<const float4*>(W + (size_t)n * (D_IN * J));
      #pragma unroll
      for (int q = 0; q < 8; ++q) {
        int ls = t + q * 512;                        // logical float4 slot
        float4 w4 = Wg[ls];
        reinterpret_cast<float4*>(Wl)[swz(ls)] = w4;
      }
    }
    // ---- stage u[b_base..b_base+31][n][:], transposed ----
    if (t < 128) {
      int bl = t >> 2, iq = t & 3;
      const float4* ug = reinterpret_cast<const float4*>(
          u + ((size_t)(b_base + bl) * N_IN + n) * D_IN + iq * 4);
      float4 u4 = ug[0];
      uT[iq * 4 + 0][bl] = u4.x;
      uT[iq * 4 + 1][bl] = u4.y;
      uT[iq * 4 + 2][bl] = u4.z;
      uT[iq * 4 + 3][bl] = u4.w;
    }
    __syncthreads();   // (A) staging complete

    // ---- uhat tile: uh[bb][q] = sum_i u[b][i] * W[i][j0+q] ----
    float uh[BT][JT];
    #pragma unroll
    for (int bb = 0; bb < BT; ++bb)
      #pragma unroll
      for (int q = 0; q < JT; ++q) uh[bb][q] = 0.f;

    #pragma unroll
    for (int i = 0; i < 16; ++i) {
      int base = i * 256 + jg * 2;
      float4 w0 = reinterpret_cast<const float4*>(Wl)[swz(base)];
      float4 w1 = reinterpret_cast<const float4*>(Wl)[swz(base + 1)];
      const float4 ua = *reinterpret_cast<const float4*>(&uT[i][bl0]);
      const float4 ub = *reinterpret_cast<const float4*>(&uT[i][bl0 + 4]);
      float us[8] = {ua.x, ua.y, ua.z, ua.w, ub.x, ub.y, ub.z, ub.w};
      #pragma unroll
      for (int bb = 0; bb < BT; ++bb) {
        uh[bb][0] += us[bb] * w0.x; uh[bb][1] += us[bb] * w0.y;
        uh[bb][2] += us[bb] * w0.z; uh[bb][3] += us[bb] * w0.w;
        uh[bb][4] += us[bb] * w1.x; uh[bb][5] += us[bb] * w1.y;
        uh[bb][6] += us[bb] * w1.z; uh[bb][7] += us[bb] * w1.w;
      }
    }

    if (HAS_V) {
      // agreement a[b][o] = sum_k uhat*v ; each thread has 8 of the 32 k's
      float ap[BT];
      #pragma unroll
      for (int bb = 0; bb < BT; ++bb) {
        float s = 0.f;
        #pragma unroll
        for (int q = 0; q < JT; ++q) s += uh[bb][q] * vr[bb][q];
        s += __shfl_xor(s, 1);
        s += __shfl_xor(s, 2);
        ap[bb] = s;
      }
      if ((jg & 3) == 0) {
        #pragma unroll
        for (int bb = 0; bb < BT; ++bb) al[bl0 + bb][o] = ap[bb];
      }
      __syncthreads();  // (B) logits staged

      // softmax over o (32 rows x 32 cols), 16 lanes per row
      {
        int br = t >> 4, ol = t & 15;
        float x0 = al[br][ol], x1 = al[br][ol + 16];
        float m = fmaxf(x0, x1);
        #pragma unroll
        for (int k = 1; k < 16; k <<= 1) m = fmaxf(m, __shfl_xor(m, k));
        float e0 = __expf(x0 - m), e1 = __expf(x1 - m);
        float sm = e0 + e1;
        #pragma unroll
        for (int k = 1; k < 16; k <<= 1) sm += __shfl_xor(sm, k);
        float r = 1.f / sm;
        al[br][ol] = e0 * r;
        al[br][ol + 16] = e1 * r;
      }
      __syncthreads();  // (C) c ready

      #pragma unroll
      for (int bb = 0; bb < BT; ++bb) {
        float c = al[bl0 + bb][o];
        #pragma unroll
        for (int q = 0; q < JT; ++q) acc[bb][q] += c * uh[bb][q];
      }
    } else {
      // pass 0: c uniform (1/32 applied at squash)
      #pragma unroll
      for (int bb = 0; bb < BT; ++bb)
        #pragma unroll
        for (int q = 0; q < JT; ++q) acc[bb][q] += uh[bb][q];
      __syncthreads();  // protect Wl/uT before next stage (HAS_V path is protected by B)
    }
  }

  // ---- flush partial s via atomics ----
  #pragma unroll
  for (int bb = 0; bb < BT; ++bb) {
    float* dst = s_out + (size_t)(b_base + bl0 + bb) * J + j0;
    #pragma unroll
    for (int q = 0; q < JT; ++q) atomicAdd(dst + q, acc[bb][q]);
  }
}

// v = squash(prescale * s) [+ addv] ; one block per batch element, 1024 threads
__global__ void squash_kernel(const float* __restrict__ s, const float* __restrict__ addv,
                              float* __restrict__ out, float prescale)
{
  int b = blockIdx.x;
  int t = threadIdx.x;                 // t = o*32 + k
  int idx = b * J + t;
  float x = s[idx] * prescale;
  float n2 = x * x;
  #pragma unroll
  for (int k = 1; k < 32; k <<= 1) n2 += __shfl_xor(n2, k);
  float sc = sqrtf(n2) / (1.f + n2);   // norm2/(1+norm2)/sqrt(norm2)
  float val = sc * x;
  if (addv) val += addv[idx];
  out[idx] = val;
}

extern "C" void kernel_launch(void* const* d_in, const int* in_sizes, int n_in,
                              void* d_out, int out_size, void* d_ws, size_t ws_size,
                              hipStream_t stream)
{
  const float* u = (const float*)d_in[0];
  const float* W = (const float*)d_in[1];
  float* ws = (float*)d_ws;
  float* s0 = ws;                 // 65536
  float* s1 = ws + 65536;
  float* s2 = ws + 131072;
  float* v0 = ws + 196608;
  float* vs = ws + 262144;        // v0 + v1
  float* out = (float*)d_out;

  hipMemsetAsync(ws, 0, (size_t)3 * 65536 * sizeof(float), stream);

  dim3 grid(N_IN / NCHUNK, 2);

  // r=0: c uniform -> s0 = sum_n uhat ; v0 = squash(s0/32)
  pass_kernel<false><<<grid, BLOCK, 0, stream>>>(u, W, nullptr, s0);
  squash_kernel<<<BATCH, J, 0, stream>>>(s0, nullptr, v0, 1.f / 32.f);

  // r=1: logits = uhat.v0 -> s1 ; v1 = squash(s1); vs = v0 + v1
  pass_kernel<true><<<grid, BLOCK, 0, stream>>>(u, W, v0, s1);
  squash_kernel<<<BATCH, J, 0, stream>>>(s1, v0, vs, 1.f);

  // r=2: logits = uhat.(v0+v1) -> s2 ; out = squash(s2)
  pass_kernel<true><<<grid, BLOCK, 0, stream>>>(u, W, vs, s2);
  squash_kernel<<<BATCH, J, 0, stream>>>(s2, nullptr, out, 1.f);
}

// Round 2
// 1063.483 us; speedup vs baseline: 1.6413x; 1.6413x over previous
//
#include <hip/hip_runtime.h>
#include <math.h>

#define N_OUT 32
#define D_OUT 32
#define N_IN 2048
#define D_IN 16
#define BATCH 64
#define J 1024           // N_OUT*D_OUT

#define BLOCK 512
#define BT 8             // b per thread
#define JT 8             // j per thread

__device__ __forceinline__ int swz(int slot) { return slot ^ ((slot >> 3) & 7); }

// Each block: 32 b (one half of batch) x all 1024 j, NCHUNK consecutive n.
// Writes private partial tile part[cx][b][j] (no atomics).
template<bool HAS_V, int NCHUNK>
__global__ __launch_bounds__(BLOCK, 4)
void pass_kernel(const float* __restrict__ u, const float* __restrict__ W,
                 const float* __restrict__ vin, float* __restrict__ part)
{
  __shared__ float Wl[16 * 1024];   // swizzled float4-slots
  __shared__ float uT[16][36];      // [i][b_local], rows 144B (16B-aligned)
  __shared__ float al[32][32];      // logits -> softmax c

  const int t   = threadIdx.x;
  const int jg  = t & 127;          // j-group (8 j each)
  const int j0  = jg * JT;
  const int bg  = t >> 7;           // 0..3
  const int bl0 = bg * BT;

  // XCD-paired decode: the two blocks sharing cx have ids 8 apart -> same XCD L2
  const int bid = blockIdx.x;
  const int cy  = (bid >> 3) & 1;
  const int cx  = (bid & 7) | ((bid >> 4) << 3);

  const int b_base = cy * 32;
  const int n0  = cx * NCHUNK;
  const int o   = jg >> 2;          // output capsule (4 lanes share one o)

  float vr[BT][JT];
  if (HAS_V) {
    #pragma unroll
    for (int bb = 0; bb < BT; ++bb) {
      const float4* vp = reinterpret_cast<const float4*>(vin + (size_t)(b_base + bl0 + bb) * J + j0);
      float4 a = vp[0], b4 = vp[1];
      vr[bb][0] = a.x;  vr[bb][1] = a.y;  vr[bb][2] = a.z;  vr[bb][3] = a.w;
      vr[bb][4] = b4.x; vr[bb][5] = b4.y; vr[bb][6] = b4.z; vr[bb][7] = b4.w;
    }
  }

  float acc[BT][JT];
  #pragma unroll
  for (int bb = 0; bb < BT; ++bb)
    #pragma unroll
    for (int q = 0; q < JT; ++q) acc[bb][q] = 0.f;

  for (int nn = 0; nn < NCHUNK; ++nn) {
    const int n = n0 + nn;

    // ---- stage W[n] (16 x 1024 f32 = 64KB), swizzled ----
    {
      const float4* Wg = reinterpret_cast<const float4*>(W + (size_t)n * (D_IN * J));
      #pragma unroll
      for (int q = 0; q < 8; ++q) {
        int ls = t + q * 512;
        float4 w4 = Wg[ls];
        reinterpret_cast<float4*>(Wl)[swz(ls)] = w4;
      }
    }
    // ---- stage u[b_base..+31][n][:], transposed ----
    if (t < 128) {
      int bl = t >> 2, iq = t & 3;
      const float4* ug = reinterpret_cast<const float4*>(
          u + ((size_t)(b_base + bl) * N_IN + n) * D_IN + iq * 4);
      float4 u4 = ug[0];
      uT[iq * 4 + 0][bl] = u4.x;
      uT[iq * 4 + 1][bl] = u4.y;
      uT[iq * 4 + 2][bl] = u4.z;
      uT[iq * 4 + 3][bl] = u4.w;
    }
    __syncthreads();   // (A) staging complete; also separates al reads (prev iter) from al writes

    // ---- uhat tile ----
    float uh[BT][JT];
    #pragma unroll
    for (int bb = 0; bb < BT; ++bb)
      #pragma unroll
      for (int q = 0; q < JT; ++q) uh[bb][q] = 0.f;

    #pragma unroll
    for (int i = 0; i < 16; ++i) {
      int base = i * 256 + jg * 2;
      float4 w0 = reinterpret_cast<const float4*>(Wl)[swz(base)];
      float4 w1 = reinterpret_cast<const float4*>(Wl)[swz(base + 1)];
      const float4 ua = *reinterpret_cast<const float4*>(&uT[i][bl0]);
      const float4 ub = *reinterpret_cast<const float4*>(&uT[i][bl0 + 4]);
      float us[8] = {ua.x, ua.y, ua.z, ua.w, ub.x, ub.y, ub.z, ub.w};
      #pragma unroll
      for (int bb = 0; bb < BT; ++bb) {
        uh[bb][0] += us[bb] * w0.x; uh[bb][1] += us[bb] * w0.y;
        uh[bb][2] += us[bb] * w0.z; uh[bb][3] += us[bb] * w0.w;
        uh[bb][4] += us[bb] * w1.x; uh[bb][5] += us[bb] * w1.y;
        uh[bb][6] += us[bb] * w1.z; uh[bb][7] += us[bb] * w1.w;
      }
    }

    if (HAS_V) {
      float ap[BT];
      #pragma unroll
      for (int bb = 0; bb < BT; ++bb) {
        float s = 0.f;
        #pragma unroll
        for (int q = 0; q < JT; ++q) s += uh[bb][q] * vr[bb][q];
        s += __shfl_xor(s, 1);
        s += __shfl_xor(s, 2);
        ap[bb] = s;
      }
      if ((jg & 3) == 0) {
        #pragma unroll
        for (int bb = 0; bb < BT; ++bb) al[bl0 + bb][o] = ap[bb];
      }
      __syncthreads();  // (B) logits staged

      {
        int br = t >> 4, ol = t & 15;
        float x0 = al[br][ol], x1 = al[br][ol + 16];
        float m = fmaxf(x0, x1);
        #pragma unroll
        for (int k = 1; k < 16; k <<= 1) m = fmaxf(m, __shfl_xor(m, k));
        float e0 = __expf(x0 - m), e1 = __expf(x1 - m);
        float sm = e0 + e1;
        #pragma unroll
        for (int k = 1; k < 16; k <<= 1) sm += __shfl_xor(sm, k);
        float r = 1.f / sm;
        al[br][ol] = e0 * r;
        al[br][ol + 16] = e1 * r;
      }
      __syncthreads();  // (C) c ready

      #pragma unroll
      for (int bb = 0; bb < BT; ++bb) {
        float c = al[bl0 + bb][o];
        #pragma unroll
        for (int q = 0; q < JT; ++q) acc[bb][q] += c * uh[bb][q];
      }
    } else {
      #pragma unroll
      for (int bb = 0; bb < BT; ++bb)
        #pragma unroll
        for (int q = 0; q < JT; ++q) acc[bb][q] += uh[bb][q];
      __syncthreads();  // protect Wl/uT before next stage
    }
  }

  // ---- flush partial s: plain coalesced stores, no atomics ----
  {
    float* dst = part + ((size_t)cx * BATCH + b_base + bl0) * J + j0;
    #pragma unroll
    for (int bb = 0; bb < BT; ++bb) {
      float4 lo = make_float4(acc[bb][0], acc[bb][1], acc[bb][2], acc[bb][3]);
      float4 hi = make_float4(acc[bb][4], acc[bb][5], acc[bb][6], acc[bb][7]);
      float4* p = reinterpret_cast<float4*>(dst + (size_t)bb * J);
      p[0] = lo; p[1] = hi;
    }
  }
}

// Fused chunk-reduce + squash. grid = (64 b * 4 jq) blocks x 256 threads.
// out = squash(prescale * sum_c part[c][b][j]) (+ addv)
template<int C>
__global__ void squash_kernel(const float* __restrict__ part, const float* __restrict__ addv,
                              float* __restrict__ out, float prescale)
{
  const int b  = blockIdx.x >> 2;
  const int jq = blockIdx.x & 3;
  const int t  = threadIdx.x;
  const int j  = jq * 256 + t;
  const float* p = part + (size_t)b * J + j;
  float s = 0.f;
  #pragma unroll 8
  for (int c = 0; c < C; ++c) s += p[(size_t)c * (BATCH * J)];
  float x = s * prescale;
  float n2 = x * x;
  #pragma unroll
  for (int k = 1; k < 32; k <<= 1) n2 += __shfl_xor(n2, k);   // within 32-lane halves = one o
  float sc = sqrtf(n2) / (1.f + n2);
  float val = sc * x;
  int idx = b * J + j;
  if (addv) val += addv[idx];
  out[idx] = val;
}

template<int NCHUNK>
static void run_all(const float* u, const float* W, float* ws, float* out, hipStream_t stream)
{
  constexpr int NC = N_IN / NCHUNK;          // chunk count (multiple of 8)
  float* part = ws;                          // NC * 64 * 1024 floats
  float* v0 = ws + (size_t)NC * BATCH * J;
  float* vs = v0 + BATCH * J;

  dim3 grid(2 * NC);

  // r=0: c uniform -> s0 = sum_n uhat ; v0 = squash(s0/32)
  pass_kernel<false, NCHUNK><<<grid, BLOCK, 0, stream>>>(u, W, nullptr, part);
  squash_kernel<NC><<<BATCH * 4, 256, 0, stream>>>(part, nullptr, v0, 1.f / 32.f);

  // r=1: logits = uhat.v0 ; vs = v0 + squash(s1)
  pass_kernel<true, NCHUNK><<<grid, BLOCK, 0, stream>>>(u, W, v0, part);
  squash_kernel<NC><<<BATCH * 4, 256, 0, stream>>>(part, v0, vs, 1.f);

  // r=2: logits = uhat.(v0+v1) ; out = squash(s2)
  pass_kernel<true, NCHUNK><<<grid, BLOCK, 0, stream>>>(u, W, vs, part);
  squash_kernel<NC><<<BATCH * 4, 256, 0, stream>>>(part, nullptr, out, 1.f);
}

extern "C" void kernel_launch(void* const* d_in, const int* in_sizes, int n_in,
                              void* d_out, int out_size, void* d_ws, size_t ws_size,
                              hipStream_t stream)
{
  const float* u = (const float*)d_in[0];
  const float* W = (const float*)d_in[1];
  float* ws = (float*)d_ws;
  float* out = (float*)d_out;

  auto need = [](int nchunk) -> size_t {
    size_t nc = N_IN / nchunk;
    return (nc * BATCH * J + 2ull * BATCH * J) * sizeof(float);
  };

  if (ws_size >= need(8))        run_all<8>(u, W, ws, out, stream);
  else if (ws_size >= need(16))  run_all<16>(u, W, ws, out, stream);
  else if (ws_size >= need(32))  run_all<32>(u, W, ws, out, stream);
  else if (ws_size >= need(64))  run_all<64>(u, W, ws, out, stream);
  else                           run_all<128>(u, W, ws, out, stream);
}

// Round 3
// 402.925 us; speedup vs baseline: 4.3320x; 2.6394x over previous
//
#include <hip/hip_runtime.h>
#include <math.h>

#define N_OUT 32
#define D_OUT 32
#define N_IN 2048
#define D_IN 16
#define BATCH 64
#define J 1024           // N_OUT*D_OUT

#define BLOCK 512
#define BT 4             // b per thread  (16 b per block)
#define JT 8             // j per thread  (1024 j per block)

__device__ __forceinline__ int swz(int slot) { return slot ^ ((slot >> 3) & 7); }

// Block: 16 b (one quadrant of batch) x all 1024 j, NCHUNK consecutive n.
// Per-thread state: acc[4][8] + uh[4][8] + vr[4][8] = 96 floats -> fits 128 VGPR.
// The 4 b-quadrant blocks of one chunk are placed on the same XCD (ids = cx mod 8)
// so the 64KB W[n] stage is fetched once into that XCD's L2.
template<bool HAS_V, int NCHUNK>
__global__ __launch_bounds__(BLOCK, 2)
void pass_kernel(const float* __restrict__ u, const float* __restrict__ W,
                 const float* __restrict__ vin, float* __restrict__ part)
{
  __shared__ float Wl[16 * 1024];   // swizzled float4-slots (64 KB)
  __shared__ float uT[16][20];      // [i][b_local], padded rows (80 B, 16B-aligned)
  __shared__ float al[16][32];      // logits -> softmax c

  const int t   = threadIdx.x;
  const int jg  = t & 127;          // j-group (8 j each)
  const int j0  = jg * JT;
  const int bg  = t >> 7;           // 0..3
  const int bl0 = bg * BT;

  // XCD grouping: 4 blocks sharing cx have ids {x, x+8, x+16, x+24} -> same XCD
  const int bid = blockIdx.x;
  const int cy  = (bid >> 3) & 3;                    // b-quadrant
  const int cx  = (bid & 7) | ((bid >> 5) << 3);     // chunk index

  const int b_base = cy * 16;
  const int n0  = cx * NCHUNK;
  const int o   = jg >> 2;          // output capsule (4 lanes share one o)

  float vr[BT][JT];
  if (HAS_V) {
    #pragma unroll
    for (int bb = 0; bb < BT; ++bb) {
      const float4* vp = reinterpret_cast<const float4*>(vin + (size_t)(b_base + bl0 + bb) * J + j0);
      float4 a = vp[0], b4 = vp[1];
      vr[bb][0] = a.x;  vr[bb][1] = a.y;  vr[bb][2] = a.z;  vr[bb][3] = a.w;
      vr[bb][4] = b4.x; vr[bb][5] = b4.y; vr[bb][6] = b4.z; vr[bb][7] = b4.w;
    }
  }

  float acc[BT][JT];
  #pragma unroll
  for (int bb = 0; bb < BT; ++bb)
    #pragma unroll
    for (int q = 0; q < JT; ++q) acc[bb][q] = 0.f;

  for (int nn = 0; nn < NCHUNK; ++nn) {
    const int n = n0 + nn;

    // ---- stage W[n] (16 x 1024 f32 = 64KB), swizzled ----
    {
      const float4* Wg = reinterpret_cast<const float4*>(W + (size_t)n * (D_IN * J));
      #pragma unroll
      for (int q = 0; q < 8; ++q) {
        int ls = t + q * 512;
        float4 w4 = Wg[ls];
        reinterpret_cast<float4*>(Wl)[swz(ls)] = w4;
      }
    }
    // ---- stage u[b_base..+15][n][:], transposed ----
    if (t < 64) {
      int bl = t >> 2, iq = t & 3;
      const float4* ug = reinterpret_cast<const float4*>(
          u + ((size_t)(b_base + bl) * N_IN + n) * D_IN + iq * 4);
      float4 u4 = ug[0];
      uT[iq * 4 + 0][bl] = u4.x;
      uT[iq * 4 + 1][bl] = u4.y;
      uT[iq * 4 + 2][bl] = u4.z;
      uT[iq * 4 + 3][bl] = u4.w;
    }
    __syncthreads();   // (A) staging complete

    // ---- uhat tile: uh[bb][q] = sum_i u[b][i] * W[i][j0+q] ----
    float uh[BT][JT];
    #pragma unroll
    for (int bb = 0; bb < BT; ++bb)
      #pragma unroll
      for (int q = 0; q < JT; ++q) uh[bb][q] = 0.f;

    #pragma unroll
    for (int i = 0; i < 16; ++i) {
      int base = i * 256 + jg * 2;
      float4 w0 = reinterpret_cast<const float4*>(Wl)[swz(base)];
      float4 w1 = reinterpret_cast<const float4*>(Wl)[swz(base + 1)];
      const float4 ua = *reinterpret_cast<const float4*>(&uT[i][bl0]);
      float us[4] = {ua.x, ua.y, ua.z, ua.w};
      #pragma unroll
      for (int bb = 0; bb < BT; ++bb) {
        uh[bb][0] += us[bb] * w0.x; uh[bb][1] += us[bb] * w0.y;
        uh[bb][2] += us[bb] * w0.z; uh[bb][3] += us[bb] * w0.w;
        uh[bb][4] += us[bb] * w1.x; uh[bb][5] += us[bb] * w1.y;
        uh[bb][6] += us[bb] * w1.z; uh[bb][7] += us[bb] * w1.w;
      }
    }

    if (HAS_V) {
      // agreement a[b][o] = sum_k uhat*v ; each thread has 8 of the 32 k's
      float ap[BT];
      #pragma unroll
      for (int bb = 0; bb < BT; ++bb) {
        float s = 0.f;
        #pragma unroll
        for (int q = 0; q < JT; ++q) s += uh[bb][q] * vr[bb][q];
        s += __shfl_xor(s, 1);
        s += __shfl_xor(s, 2);
        ap[bb] = s;
      }
      if ((jg & 3) == 0) {
        #pragma unroll
        for (int bb = 0; bb < BT; ++bb) al[bl0 + bb][o] = ap[bb];
      }
      __syncthreads();  // (B) logits staged

      // softmax over o: one thread per (b,o), 32-lane groups reduce
      {
        int br = t >> 5, ol = t & 31;
        float x = al[br][ol];
        float m = x;
        #pragma unroll
        for (int k = 1; k < 32; k <<= 1) m = fmaxf(m, __shfl_xor(m, k));
        float e = __expf(x - m);
        float sm = e;
        #pragma unroll
        for (int k = 1; k < 32; k <<= 1) sm += __shfl_xor(sm, k);
        al[br][ol] = e / sm;
      }
      __syncthreads();  // (C) c ready

      #pragma unroll
      for (int bb = 0; bb < BT; ++bb) {
        float c = al[bl0 + bb][o];
        #pragma unroll
        for (int q = 0; q < JT; ++q) acc[bb][q] += c * uh[bb][q];
      }
    } else {
      #pragma unroll
      for (int bb = 0; bb < BT; ++bb)
        #pragma unroll
        for (int q = 0; q < JT; ++q) acc[bb][q] += uh[bb][q];
      __syncthreads();  // protect Wl/uT before next stage
    }
  }

  // ---- flush partial s: plain coalesced float4 stores ----
  {
    float* dst = part + ((size_t)cx * BATCH + b_base + bl0) * J + j0;
    #pragma unroll
    for (int bb = 0; bb < BT; ++bb) {
      float4 lo = make_float4(acc[bb][0], acc[bb][1], acc[bb][2], acc[bb][3]);
      float4 hi = make_float4(acc[bb][4], acc[bb][5], acc[bb][6], acc[bb][7]);
      float4* p = reinterpret_cast<float4*>(dst + (size_t)bb * J);
      p[0] = lo; p[1] = hi;
    }
  }
}

// Fused chunk-reduce + squash. grid = (64 b * 4 jq) blocks x 256 threads.
template<int C>
__global__ void squash_kernel(const float* __restrict__ part, const float* __restrict__ addv,
                              float* __restrict__ out, float prescale)
{
  const int b  = blockIdx.x >> 2;
  const int jq = blockIdx.x & 3;
  const int t  = threadIdx.x;
  const int j  = jq * 256 + t;
  const float* p = part + (size_t)b * J + j;
  float s = 0.f;
  #pragma unroll 8
  for (int c = 0; c < C; ++c) s += p[(size_t)c * (BATCH * J)];
  float x = s * prescale;
  float n2 = x * x;
  #pragma unroll
  for (int k = 1; k < 32; k <<= 1) n2 += __shfl_xor(n2, k);   // 32-lane group = one o
  float sc = sqrtf(n2) / (1.f + n2);
  float val = sc * x;
  int idx = b * J + j;
  if (addv) val += addv[idx];
  out[idx] = val;
}

template<int NCHUNK>
static void run_all(const float* u, const float* W, float* ws, float* out, hipStream_t stream)
{
  constexpr int NC = N_IN / NCHUNK;          // chunk count
  float* part = ws;                          // NC * 64 * 1024 floats
  float* v0 = ws + (size_t)NC * BATCH * J;
  float* vs = v0 + BATCH * J;

  dim3 grid(4 * NC);

  // r=0: c uniform -> s0 = sum_n uhat ; v0 = squash(s0/32)
  pass_kernel<false, NCHUNK><<<grid, BLOCK, 0, stream>>>(u, W, nullptr, part);
  squash_kernel<NC><<<BATCH * 4, 256, 0, stream>>>(part, nullptr, v0, 1.f / 32.f);

  // r=1: logits = uhat.v0 ; vs = v0 + squash(s1)
  pass_kernel<true, NCHUNK><<<grid, BLOCK, 0, stream>>>(u, W, v0, part);
  squash_kernel<NC><<<BATCH * 4, 256, 0, stream>>>(part, v0, vs, 1.f);

  // r=2: logits = uhat.(v0+v1) ; out = squash(s2)
  pass_kernel<true, NCHUNK><<<grid, BLOCK, 0, stream>>>(u, W, vs, part);
  squash_kernel<NC><<<BATCH * 4, 256, 0, stream>>>(part, nullptr, out, 1.f);
}

extern "C" void kernel_launch(void* const* d_in, const int* in_sizes, int n_in,
                              void* d_out, int out_size, void* d_ws, size_t ws_size,
                              hipStream_t stream)
{
  const float* u = (const float*)d_in[0];
  const float* W = (const float*)d_in[1];
  float* ws = (float*)d_ws;
  float* out = (float*)d_out;

  auto need = [](int nchunk) -> size_t {
    size_t nc = N_IN / nchunk;
    return (nc * BATCH * J + 2ull * BATCH * J) * sizeof(float);
  };

  if (ws_size >= need(16))       run_all<16>(u, W, ws, out, stream);
  else if (ws_size >= need(32))  run_all<32>(u, W, ws, out, stream);
  else if (ws_size >= need(64))  run_all<64>(u, W, ws, out, stream);
  else                           run_all<128>(u, W, ws, out, stream);
}

// Round 4
// 224.806 us; speedup vs baseline: 7.7643x; 1.7923x over previous
//
#include <hip/hip_runtime.h>
#include <math.h>

#define N_OUT 32
#define D_OUT 32
#define N_IN 2048
#define D_IN 16
#define BATCH 64
#define J 1024           // N_OUT*D_OUT

typedef __attribute__((ext_vector_type(8))) short short8;   // 8 bf16 (4 VGPR)
typedef __attribute__((ext_vector_type(4))) float f32x4;    // MFMA C/D

// f32 -> bf16 RNE
__device__ __forceinline__ unsigned short f2bf(float f) {
  unsigned int x = __float_as_uint(f);
  unsigned int r = (x + 0x7FFFu + ((x >> 16) & 1u)) >> 16;
  return (unsigned short)r;
}

// 16B-unit swizzle inside one n-tile (2048 units): XOR bit0 with bit3
__device__ __forceinline__ int wp(int u) { return u ^ ((u >> 3) & 1); }

__device__ __forceinline__ void pack_col(const float* wc, uint4& d0, uint4& d1) {
  d0.x = (unsigned)f2bf(wc[0])  | ((unsigned)f2bf(wc[1])  << 16);
  d0.y = (unsigned)f2bf(wc[2])  | ((unsigned)f2bf(wc[3])  << 16);
  d0.z = (unsigned)f2bf(wc[4])  | ((unsigned)f2bf(wc[5])  << 16);
  d0.w = (unsigned)f2bf(wc[6])  | ((unsigned)f2bf(wc[7])  << 16);
  d1.x = (unsigned)f2bf(wc[8])  | ((unsigned)f2bf(wc[9])  << 16);
  d1.y = (unsigned)f2bf(wc[10]) | ((unsigned)f2bf(wc[11]) << 16);
  d1.z = (unsigned)f2bf(wc[12]) | ((unsigned)f2bf(wc[13]) << 16);
  d1.w = (unsigned)f2bf(wc[14]) | ((unsigned)f2bf(wc[15]) << 16);
}

// W[n][i][j] f32 -> Wbf[n][swizzled 16B units of (j,i-half)] bf16 (transposed)
__global__ void prep_w(const float* __restrict__ Wf, short* __restrict__ Wbf) {
  const int n = blockIdx.x, t = threadIdx.x;            // 2048 x 256
  const float* src = Wf + (size_t)n * (D_IN * J);
  uint4* dst = reinterpret_cast<uint4*>(Wbf + (size_t)n * (D_IN * J));
  for (int q = 0; q < 4; ++q) {
    int j = q * 256 + t;
    float wc[16];
    #pragma unroll
    for (int i = 0; i < 16; ++i) wc[i] = src[i * J + j];
    uint4 d0, d1;
    pack_col(wc, d0, d1);
    dst[wp(2 * j)]     = d0;   // i = 0..7
    dst[wp(2 * j + 1)] = d1;   // i = 8..15
  }
}

// u f32 -> bf16, same [b][n][i] layout
__global__ void prep_u(const float* __restrict__ uf, short* __restrict__ ubf) {
  size_t gid = (size_t)blockIdx.x * 256 + threadIdx.x;  // 2048 x 256, 4 f32 each
  float4 v = reinterpret_cast<const float4*>(uf)[gid];
  uint2 d;
  d.x = (unsigned)f2bf(v.x) | ((unsigned)f2bf(v.y) << 16);
  d.y = (unsigned)f2bf(v.z) | ((unsigned)f2bf(v.w) << 16);
  reinterpret_cast<uint2*>(ubf)[gid] = d;
}

// Block: 1024 threads (16 waves), covers 16 b (one bq) x all 1024 j x NCHUNK n.
// Wave w owns jt = w*4+q (q=0..3) -> o = w*2 + (q>>1).
// MFMA swapped: D[j_loc][b_loc] = sum_i W[n][i][j] * u[b][n][i], K=16 of 32 (zero-pad).
template<bool HAS_V, bool PREP, int NCHUNK>
__global__ __launch_bounds__(1024, 1)
void pass_kernel(const float* __restrict__ uf, const float* __restrict__ Wf,
                 const short* __restrict__ Wbf, const short* __restrict__ ubf,
                 const float* __restrict__ vin, float* __restrict__ part)
{
  __shared__ uint4 Wt[2][2048];     // double-buffered W tile (2 x 32KB)
  __shared__ float al[32][18];      // logits -> c, [o][b_local]

  const int t  = threadIdx.x;
  const int l  = t & 63;
  const int w  = t >> 6;            // wave 0..15
  const int bid = blockIdx.x;
  const int bq = (bid >> 3) & 3;                    // b quadrant (16 b)
  const int cx = (bid & 7) | ((bid >> 5) << 3);     // chunk (XCD-grouped)
  const int n0 = cx * NCHUNK;

  const int bl = l & 15;            // D col = b_local
  const int b  = bq * 16 + bl;      // global b
  const int h  = l >> 4;            // 0..3: D row group (rows 4h..4h+3)
  const int hA = h & 1;             // A/B k-half (i 0-7 / 8-15), lanes<32
  const bool ld = (l < 32);

  // A 16B-unit offsets (within one buffer) per q
  int aoff[4];
  #pragma unroll
  for (int q = 0; q < 4; ++q) {
    int jt = w * 4 + q;
    int unit = 2 * (jt * 16 + bl) + hA;
    aoff[q] = wp(unit);
  }

  // v fragments (n-independent): v[b][jt*16 + 4h + r]
  f32x4 vf[4];
  if (HAS_V) {
    #pragma unroll
    for (int q = 0; q < 4; ++q) {
      int jt = w * 4 + q;
      vf[q] = *reinterpret_cast<const f32x4*>(vin + (size_t)b * J + jt * 16 + h * 4);
    }
  }

  f32x4 acc[4];
  #pragma unroll
  for (int q = 0; q < 4; ++q) acc[q] = f32x4{0.f, 0.f, 0.f, 0.f};

  // ---- prologue: stage n0 into buf 0; load B-frag for n0 ----
  short8 Bcur = short8{0,0,0,0,0,0,0,0};
  if (PREP) {
    const uint4* src = reinterpret_cast<const uint4*>(Wbf + (size_t)n0 * (D_IN * J));
    Wt[0][t] = src[t];
    Wt[0][t + 1024] = src[t + 1024];
    if (ld)
      Bcur = *reinterpret_cast<const short8*>(ubf + ((size_t)b * N_IN + n0) * D_IN + hA * 8);
  } else {
    float wc[16];
    #pragma unroll
    for (int i = 0; i < 16; ++i) wc[i] = Wf[(size_t)n0 * (D_IN * J) + i * J + t];
    uint4 d0, d1;
    pack_col(wc, d0, d1);
    Wt[0][wp(2 * t)] = d0;
    Wt[0][wp(2 * t + 1)] = d1;
    if (ld) {
      const float* up = uf + ((size_t)b * N_IN + n0) * D_IN + hA * 8;
      float4 a4 = *reinterpret_cast<const float4*>(up);
      float4 b4 = *reinterpret_cast<const float4*>(up + 4);
      Bcur[0] = (short)f2bf(a4.x); Bcur[1] = (short)f2bf(a4.y);
      Bcur[2] = (short)f2bf(a4.z); Bcur[3] = (short)f2bf(a4.w);
      Bcur[4] = (short)f2bf(b4.x); Bcur[5] = (short)f2bf(b4.y);
      Bcur[6] = (short)f2bf(b4.z); Bcur[7] = (short)f2bf(b4.w);
    }
  }
  __syncthreads();

  for (int nn = 0; nn < NCHUNK; ++nn) {
    const int n = n0 + nn;
    const int cur = nn & 1, nxt = cur ^ 1;
    const bool more = (nn + 1 < NCHUNK);

    // 1. issue next-tile loads early (write-late below)
    uint4 s0, s1;
    short8 Bn = short8{0,0,0,0,0,0,0,0};
    float wc[16];
    if (more) {
      if (PREP) {
        const uint4* src = reinterpret_cast<const uint4*>(Wbf + (size_t)(n + 1) * (D_IN * J));
        s0 = src[t];
        s1 = src[t + 1024];
        if (ld)
          Bn = *reinterpret_cast<const short8*>(ubf + ((size_t)b * N_IN + n + 1) * D_IN + hA * 8);
      } else {
        #pragma unroll
        for (int i = 0; i < 16; ++i) wc[i] = Wf[(size_t)(n + 1) * (D_IN * J) + i * J + t];
        if (ld) {
          const float* up = uf + ((size_t)b * N_IN + n + 1) * D_IN + hA * 8;
          float4 a4 = *reinterpret_cast<const float4*>(up);
          float4 b4 = *reinterpret_cast<const float4*>(up + 4);
          Bn[0] = (short)f2bf(a4.x); Bn[1] = (short)f2bf(a4.y);
          Bn[2] = (short)f2bf(a4.z); Bn[3] = (short)f2bf(a4.w);
          Bn[4] = (short)f2bf(b4.x); Bn[5] = (short)f2bf(b4.y);
          Bn[6] = (short)f2bf(b4.z); Bn[7] = (short)f2bf(b4.w);
        }
      }
    }

    // 2. uhat tiles via MFMA
    f32x4 C[4];
    const uint4* buf = Wt[cur];
    #pragma unroll
    for (int q = 0; q < 4; ++q) {
      short8 A = short8{0,0,0,0,0,0,0,0};
      if (ld) A = *reinterpret_cast<const short8*>(&buf[aoff[q]]);
      f32x4 z = f32x4{0.f, 0.f, 0.f, 0.f};
      C[q] = __builtin_amdgcn_mfma_f32_16x16x32_bf16(A, Bcur, z, 0, 0, 0);
    }

    if (HAS_V) {
      // 3. agreement a[b][o] = sum_k uhat*v  (k spread over regs+h-groups)
      float ap[2] = {0.f, 0.f};
      #pragma unroll
      for (int q = 0; q < 4; ++q) {
        float s = C[q][0] * vf[q][0] + C[q][1] * vf[q][1]
                + C[q][2] * vf[q][2] + C[q][3] * vf[q][3];
        ap[q >> 1] += s;
      }
      #pragma unroll
      for (int p = 0; p < 2; ++p) {
        float s = ap[p];
        s += __shfl_xor(s, 16);
        s += __shfl_xor(s, 32);
        if (l < 16) al[w * 2 + p][l] = s;
      }
    } else {
      #pragma unroll
      for (int q = 0; q < 4; ++q) acc[q] += C[q];
    }

    // 4. write-late staging into other buffer
    if (more) {
      if (PREP) {
        Wt[nxt][t] = s0;
        Wt[nxt][t + 1024] = s1;
      } else {
        uint4 d0, d1;
        pack_col(wc, d0, d1);
        Wt[nxt][wp(2 * t)] = d0;
        Wt[nxt][wp(2 * t + 1)] = d1;
      }
    }

    if (HAS_V) {
      __syncthreads();   // (B) logits staged
      if (t < 512) {     // softmax over o per (b): 32-lane o-groups
        int sb = t >> 5, so = t & 31;
        float x = al[so][sb];
        float m = x;
        #pragma unroll
        for (int k = 1; k < 32; k <<= 1) m = fmaxf(m, __shfl_xor(m, k));
        float e = __expf(x - m);
        float sm = e;
        #pragma unroll
        for (int k = 1; k < 32; k <<= 1) sm += __shfl_xor(sm, k);
        al[so][sb] = e / sm;
      }
      __syncthreads();   // (C) c ready
      #pragma unroll
      for (int q = 0; q < 4; ++q) {
        float c = al[(w * 4 + q) >> 1][bl];
        acc[q] += C[q] * c;
      }
    }

    Bcur = Bn;
    __syncthreads();     // (D) protect al reads & staged buffer
  }

  // epilogue: part_t[cx][j][b] (transposed -> full-line writes)
  #pragma unroll
  for (int q = 0; q < 4; ++q) {
    int jbase = (w * 4 + q) * 16 + h * 4;
    #pragma unroll
    for (int r = 0; r < 4; ++r)
      part[((size_t)cx * J + jbase + r) * 64 + b] = acc[q][r];
  }
}

// sum over chunks: s[b][j] = sum_c part[c][j][b]
template<int NC>
__global__ void reduce_kernel(const float* __restrict__ part, float* __restrict__ s) {
  const int t = threadIdx.x;          // 256
  const int b = t & 63, jl = t >> 6;
  const int j = blockIdx.x * 4 + jl;  // grid 256
  const float* p = part + (size_t)j * 64 + b;
  float acc = 0.f;
  #pragma unroll 8
  for (int c = 0; c < NC; ++c) acc += p[(size_t)c * (J * 64)];
  s[(size_t)b * J + j] = acc;
}

// v = squash(prescale * s) [+ addv]
__global__ void squash_kernel(const float* __restrict__ s, const float* __restrict__ addv,
                              float* __restrict__ out, float prescale)
{
  const int bb = blockIdx.x;          // 64
  const int t = threadIdx.x;          // 1024
  const int idx = bb * J + t;
  float x = s[idx] * prescale;
  float n2 = x * x;
  #pragma unroll
  for (int k = 1; k < 32; k <<= 1) n2 += __shfl_xor(n2, k);  // 32-lane group = one o
  float sc = sqrtf(n2) / (1.f + n2);
  float val = sc * x;
  if (addv) val += addv[idx];
  out[idx] = val;
}

template<bool PREP, int NCHUNK>
static void run_passes(const float* u, const float* W, const short* Wbf, const short* ubf,
                       float* part, float* sbuf, float* v0, float* vs, float* out,
                       hipStream_t stream)
{
  constexpr int NC = N_IN / NCHUNK;
  dim3 grid(4 * NC);
  // r=0: c uniform
  pass_kernel<false, PREP, NCHUNK><<<grid, 1024, 0, stream>>>(u, W, Wbf, ubf, nullptr, part);
  reduce_kernel<NC><<<256, 256, 0, stream>>>(part, sbuf);
  squash_kernel<<<BATCH, 1024, 0, stream>>>(sbuf, nullptr, v0, 1.f / 32.f);
  // r=1: logits = uhat.v0 ; vs = v0 + v1
  pass_kernel<true, PREP, NCHUNK><<<grid, 1024, 0, stream>>>(u, W, Wbf, ubf, v0, part);
  reduce_kernel<NC><<<256, 256, 0, stream>>>(part, sbuf);
  squash_kernel<<<BATCH, 1024, 0, stream>>>(sbuf, v0, vs, 1.f);
  // r=2: logits = uhat.(v0+v1)
  pass_kernel<true, PREP, NCHUNK><<<grid, 1024, 0, stream>>>(u, W, Wbf, ubf, vs, part);
  reduce_kernel<NC><<<256, 256, 0, stream>>>(part, sbuf);
  squash_kernel<<<BATCH, 1024, 0, stream>>>(sbuf, nullptr, out, 1.f);
}

extern "C" void kernel_launch(void* const* d_in, const int* in_sizes, int n_in,
                              void* d_out, int out_size, void* d_ws, size_t ws_size,
                              hipStream_t stream)
{
  const float* u = (const float*)d_in[0];
  const float* W = (const float*)d_in[1];
  float* out = (float*)d_out;
  char* ws = (char*)d_ws;

  const size_t WBF_B = (size_t)N_IN * D_IN * J * 2;        // 64 MB
  const size_t UBF_B = (size_t)BATCH * N_IN * D_IN * 2;    // 4 MB
  const size_t SMALL = 3ull * BATCH * J * 4;               // sbuf+v0+vs

  auto part_bytes = [](int nc) { return (size_t)nc * J * 64 * 4; };

  if (ws_size >= WBF_B + UBF_B + part_bytes(64) + SMALL) {
    short* Wbf = (short*)ws;
    short* ubf = (short*)(ws + WBF_B);
    float* part = (float*)(ws + WBF_B + UBF_B);
    float* sbuf = part + (size_t)64 * J * 64;
    float* v0 = sbuf + BATCH * J;
    float* vs = v0 + BATCH * J;
    prep_w<<<N_IN, 256, 0, stream>>>(W, Wbf);
    prep_u<<<2048, 256, 0, stream>>>(u, (short*)ubf);
    run_passes<true, 32>(u, W, Wbf, ubf, part, sbuf, v0, vs, out, stream);
  } else if (ws_size >= part_bytes(64) + SMALL) {
    float* part = (float*)ws;
    float* sbuf = part + (size_t)64 * J * 64;
    float* v0 = sbuf + BATCH * J;
    float* vs = v0 + BATCH * J;
    run_passes<false, 32>(u, W, nullptr, nullptr, part, sbuf, v0, vs, out, stream);
  } else if (ws_size >= part_bytes(32) + SMALL) {
    float* part = (float*)ws;
    float* sbuf = part + (size_t)32 * J * 64;
    float* v0 = sbuf + BATCH * J;
    float* vs = v0 + BATCH * J;
    run_passes<false, 64>(u, W, nullptr, nullptr, part, sbuf, v0, vs, out, stream);
  } else {
    float* part = (float*)ws;
    float* sbuf = part + (size_t)16 * J * 64;
    float* v0 = sbuf + BATCH * J;
    float* vs = v0 + BATCH * J;
    run_passes<false, 128>(u, W, nullptr, nullptr, part, sbuf, v0, vs, out, stream);
  }
}

// Round 5
// 219.781 us; speedup vs baseline: 7.9418x; 1.0229x over previous
//
#include <hip/hip_runtime.h>
#include <math.h>

#define N_OUT 32
#define D_OUT 32
#define N_IN 2048
#define D_IN 16
#define BATCH 64
#define J 1024           // N_OUT*D_OUT

typedef __attribute__((ext_vector_type(8))) short short8;   // 8 bf16 (4 VGPR)
typedef __attribute__((ext_vector_type(4))) float f32x4;    // MFMA C/D

// f32 -> bf16 RNE
__device__ __forceinline__ unsigned short f2bf(float f) {
  unsigned int x = __float_as_uint(f);
  unsigned int r = (x + 0x7FFFu + ((x >> 16) & 1u)) >> 16;
  return (unsigned short)r;
}

// 16B-unit swizzle inside one n-tile (2048 units): XOR bit0 with bit3
__device__ __forceinline__ int wp(int u) { return u ^ ((u >> 3) & 1); }

__device__ __forceinline__ void pack_col(const float* wc, uint4& d0, uint4& d1) {
  d0.x = (unsigned)f2bf(wc[0])  | ((unsigned)f2bf(wc[1])  << 16);
  d0.y = (unsigned)f2bf(wc[2])  | ((unsigned)f2bf(wc[3])  << 16);
  d0.z = (unsigned)f2bf(wc[4])  | ((unsigned)f2bf(wc[5])  << 16);
  d0.w = (unsigned)f2bf(wc[6])  | ((unsigned)f2bf(wc[7])  << 16);
  d1.x = (unsigned)f2bf(wc[8])  | ((unsigned)f2bf(wc[9])  << 16);
  d1.y = (unsigned)f2bf(wc[10]) | ((unsigned)f2bf(wc[11]) << 16);
  d1.z = (unsigned)f2bf(wc[12]) | ((unsigned)f2bf(wc[13]) << 16);
  d1.w = (unsigned)f2bf(wc[14]) | ((unsigned)f2bf(wc[15]) << 16);
}

// MODE 0: load W f32, convert in-kernel, AND write bf16 copies out (pass 0)
// MODE 1: load pre-converted Wbf/ubf (passes 1,2)
// MODE 2: load W f32, convert in-kernel, no writeout (fallback when ws too small)
//
// Block: 1024 threads (16 waves), covers 16 b (one bq) x all 1024 j x NCHUNK n.
// Wave w owns j-tiles jt = w*4+q (q=0..3) -> o = (w*4+q)>>1.
// MFMA swapped: D[j_loc][b_loc] = sum_i W[n][i][j] * u[b][n][i], K=16 of 32 (zero-pad).
template<bool HAS_V, int MODE, int NCHUNK>
__global__ __launch_bounds__(1024, 1)
void pass_kernel(const float* __restrict__ uf, const float* __restrict__ Wf,
                 short* __restrict__ Wbf, short* __restrict__ ubf,
                 const float* __restrict__ vin, float* __restrict__ part)
{
  __shared__ uint4 Wt[2][2048];     // double-buffered W tile (2 x 32KB)
  __shared__ float al[32][18];      // logits -> c, [o][b_local]

  const int t  = threadIdx.x;
  const int l  = t & 63;
  const int w  = t >> 6;            // wave 0..15
  const int bid = blockIdx.x;
  const int bq = (bid >> 3) & 3;                    // b quadrant (16 b)
  const int cx = (bid & 7) | ((bid >> 5) << 3);     // chunk (XCD-grouped)
  const int n0 = cx * NCHUNK;

  const int bl = l & 15;            // D col = b_local
  const int b  = bq * 16 + bl;      // global b
  const int h  = l >> 4;            // 0..3: D row group (rows 4h..4h+3)
  const int hA = h & 1;             // k-half (i 0-7 / 8-15) for lanes < 32
  const bool ld = (l < 32);

  // A 16B-unit offsets (within one buffer) per q
  int aoff[4];
  #pragma unroll
  for (int q = 0; q < 4; ++q) {
    int jt = w * 4 + q;
    aoff[q] = wp(2 * (jt * 16 + bl) + hA);
  }

  // v fragments (n-independent): v[b][jt*16 + 4h + r]
  f32x4 vf[4];
  if (HAS_V) {
    #pragma unroll
    for (int q = 0; q < 4; ++q) {
      int jt = w * 4 + q;
      vf[q] = *reinterpret_cast<const f32x4*>(vin + (size_t)b * J + jt * 16 + h * 4);
    }
  }

  f32x4 acc[4];
  #pragma unroll
  for (int q = 0; q < 4; ++q) acc[q] = f32x4{0.f, 0.f, 0.f, 0.f};

  const bool wq = (MODE == 0) && ((t >> 8) == bq);   // this block's Wbf quarter
  const bool uq = (MODE == 0) && (w == 0) && ld;     // wave 0 writes ubf

  // ---- prologue: stage n0 into buf 0; load B-frag for n0 ----
  short8 Bcur = short8{0,0,0,0,0,0,0,0};
  if (MODE == 1) {
    const uint4* src = reinterpret_cast<const uint4*>(Wbf + (size_t)n0 * (D_IN * J));
    Wt[0][t] = src[t];
    Wt[0][t + 1024] = src[t + 1024];
    if (ld)
      Bcur = *reinterpret_cast<const short8*>(ubf + ((size_t)b * N_IN + n0) * D_IN + hA * 8);
  } else {
    float wc[16];
    #pragma unroll
    for (int i = 0; i < 16; ++i) wc[i] = Wf[(size_t)n0 * (D_IN * J) + i * J + t];
    uint4 d0, d1;
    pack_col(wc, d0, d1);
    Wt[0][wp(2 * t)] = d0;
    Wt[0][wp(2 * t + 1)] = d1;
    if (wq) {
      uint4* gdst = reinterpret_cast<uint4*>(Wbf + (size_t)n0 * (D_IN * J));
      gdst[wp(2 * t)] = d0;
      gdst[wp(2 * t + 1)] = d1;
    }
    if (ld) {
      const float* up = uf + ((size_t)b * N_IN + n0) * D_IN + hA * 8;
      float4 a4 = *reinterpret_cast<const float4*>(up);
      float4 b4 = *reinterpret_cast<const float4*>(up + 4);
      Bcur[0] = (short)f2bf(a4.x); Bcur[1] = (short)f2bf(a4.y);
      Bcur[2] = (short)f2bf(a4.z); Bcur[3] = (short)f2bf(a4.w);
      Bcur[4] = (short)f2bf(b4.x); Bcur[5] = (short)f2bf(b4.y);
      Bcur[6] = (short)f2bf(b4.z); Bcur[7] = (short)f2bf(b4.w);
      if (uq)
        *reinterpret_cast<short8*>(ubf + ((size_t)b * N_IN + n0) * D_IN + hA * 8) = Bcur;
    }
  }
  __syncthreads();

  for (int nn = 0; nn < NCHUNK; ++nn) {
    const int n = n0 + nn;
    const int cur = nn & 1, nxt = cur ^ 1;
    const bool more = (nn + 1 < NCHUNK);

    // 1. issue next-tile loads early (write-late below)
    uint4 s0, s1;
    short8 Bn = short8{0,0,0,0,0,0,0,0};
    float wc[16];
    if (more) {
      if (MODE == 1) {
        const uint4* src = reinterpret_cast<const uint4*>(Wbf + (size_t)(n + 1) * (D_IN * J));
        s0 = src[t];
        s1 = src[t + 1024];
        if (ld)
          Bn = *reinterpret_cast<const short8*>(ubf + ((size_t)b * N_IN + n + 1) * D_IN + hA * 8);
      } else {
        #pragma unroll
        for (int i = 0; i < 16; ++i) wc[i] = Wf[(size_t)(n + 1) * (D_IN * J) + i * J + t];
        if (ld) {
          const float* up = uf + ((size_t)b * N_IN + n + 1) * D_IN + hA * 8;
          float4 a4 = *reinterpret_cast<const float4*>(up);
          float4 b4 = *reinterpret_cast<const float4*>(up + 4);
          Bn[0] = (short)f2bf(a4.x); Bn[1] = (short)f2bf(a4.y);
          Bn[2] = (short)f2bf(a4.z); Bn[3] = (short)f2bf(a4.w);
          Bn[4] = (short)f2bf(b4.x); Bn[5] = (short)f2bf(b4.y);
          Bn[6] = (short)f2bf(b4.z); Bn[7] = (short)f2bf(b4.w);
        }
      }
    }

    // 2. uhat tiles via MFMA
    f32x4 C[4];
    const uint4* buf = Wt[cur];
    #pragma unroll
    for (int q = 0; q < 4; ++q) {
      short8 A = short8{0,0,0,0,0,0,0,0};
      if (ld) A = *reinterpret_cast<const short8*>(&buf[aoff[q]]);
      f32x4 z = f32x4{0.f, 0.f, 0.f, 0.f};
      C[q] = __builtin_amdgcn_mfma_f32_16x16x32_bf16(A, Bcur, z, 0, 0, 0);
    }

    if (HAS_V) {
      // 3. agreement a[b][o] = sum_k uhat*v
      float ap[2] = {0.f, 0.f};
      #pragma unroll
      for (int q = 0; q < 4; ++q) {
        float s = C[q][0] * vf[q][0] + C[q][1] * vf[q][1]
                + C[q][2] * vf[q][2] + C[q][3] * vf[q][3];
        ap[q >> 1] += s;
      }
      #pragma unroll
      for (int p = 0; p < 2; ++p) {
        float s = ap[p];
        s += __shfl_xor(s, 16);
        s += __shfl_xor(s, 32);
        if (l < 16) al[w * 2 + p][l] = s;
      }
    } else {
      #pragma unroll
      for (int q = 0; q < 4; ++q) acc[q] += C[q];
    }

    // 4. write-late staging into other buffer (+ global writeout in MODE 0)
    if (more) {
      if (MODE == 1) {
        Wt[nxt][t] = s0;
        Wt[nxt][t + 1024] = s1;
      } else {
        uint4 d0, d1;
        pack_col(wc, d0, d1);
        Wt[nxt][wp(2 * t)] = d0;
        Wt[nxt][wp(2 * t + 1)] = d1;
        if (wq) {
          uint4* gdst = reinterpret_cast<uint4*>(Wbf + (size_t)(n + 1) * (D_IN * J));
          gdst[wp(2 * t)] = d0;
          gdst[wp(2 * t + 1)] = d1;
        }
        if (ld && uq)
          *reinterpret_cast<short8*>(ubf + ((size_t)b * N_IN + n + 1) * D_IN + hA * 8) = Bn;
      }
    }

    if (HAS_V) {
      __syncthreads();   // (B) logits staged
      if (t < 512) {     // softmax over o per b: 32-lane o-groups
        int sb = t >> 5, so = t & 31;
        float x = al[so][sb];
        float m = x;
        #pragma unroll
        for (int k = 1; k < 32; k <<= 1) m = fmaxf(m, __shfl_xor(m, k));
        float e = __expf(x - m);
        float sm = e;
        #pragma unroll
        for (int k = 1; k < 32; k <<= 1) sm += __shfl_xor(sm, k);
        al[so][sb] = e / sm;
      }
      __syncthreads();   // (C) c ready
      #pragma unroll
      for (int q = 0; q < 4; ++q) {
        float c = al[(w * 4 + q) >> 1][bl];
        acc[q] += C[q] * c;
      }
    }

    Bcur = Bn;
    __syncthreads();     // (D) protect al reads & staged buffer
  }

  // epilogue: part[cx][j][b] (transposed -> coalesced b-fast writes)
  #pragma unroll
  for (int q = 0; q < 4; ++q) {
    int jbase = (w * 4 + q) * 16 + h * 4;
    #pragma unroll
    for (int r = 0; r < 4; ++r)
      part[((size_t)cx * J + jbase + r) * 64 + b] = acc[q][r];
  }
}

// Fused chunk-reduce + squash. grid = 32 (one block per o), 1024 threads.
// out[b][o*32+k] = scale(b) * x[b][k] (+ addv), x = prescale * sum_c part[c][j][b]
template<int NC>
__global__ void rsq_kernel(const float* __restrict__ part, const float* __restrict__ addv,
                           float* __restrict__ out, float prescale)
{
  __shared__ float sl[32][65];
  __shared__ float scl[64];
  const int o  = blockIdx.x;
  const int t  = threadIdx.x;
  const int jl = t >> 6;        // 0..15
  const int b  = t & 63;

  #pragma unroll
  for (int half = 0; half < 2; ++half) {
    int k = half * 16 + jl;
    const float* p = part + (size_t)(o * 32 + k) * 64 + b;
    float s = 0.f;
    #pragma unroll 8
    for (int c = 0; c < NC; ++c) s += p[(size_t)c * (J * 64)];
    sl[k][b] = s * prescale;
  }
  __syncthreads();
  if (t < 64) {
    float n2 = 0.f;
    #pragma unroll
    for (int k = 0; k < 32; ++k) { float x = sl[k][t]; n2 += x * x; }
    scl[t] = sqrtf(n2) / (1.f + n2);
  }
  __syncthreads();
  #pragma unroll
  for (int half = 0; half < 2; ++half) {
    int b2 = (t >> 5) + half * 32;
    int k2 = t & 31;
    int idx = b2 * J + o * 32 + k2;
    float val = scl[b2] * sl[k2][b2];
    if (addv) val += addv[idx];
    out[idx] = val;
  }
}

template<int MODE0, int MODE12, int NCHUNK>
static void run_passes(const float* u, const float* W, short* Wbf, short* ubf,
                       float* part, float* v0, float* vs, float* out, hipStream_t stream)
{
  constexpr int NC = N_IN / NCHUNK;
  dim3 grid(4 * NC);
  // r=0: c uniform (pass 0 also emits bf16 W/u when MODE0==0)
  pass_kernel<false, MODE0, NCHUNK><<<grid, 1024, 0, stream>>>(u, W, Wbf, ubf, nullptr, part);
  rsq_kernel<NC><<<32, 1024, 0, stream>>>(part, nullptr, v0, 1.f / 32.f);
  // r=1: logits = uhat.v0 ; vs = v0 + squash(s1)
  pass_kernel<true, MODE12, NCHUNK><<<grid, 1024, 0, stream>>>(u, W, Wbf, ubf, v0, part);
  rsq_kernel<NC><<<32, 1024, 0, stream>>>(part, v0, vs, 1.f);
  // r=2: logits = uhat.(v0+v1) ; out = squash(s2)
  pass_kernel<true, MODE12, NCHUNK><<<grid, 1024, 0, stream>>>(u, W, Wbf, ubf, vs, part);
  rsq_kernel<NC><<<32, 1024, 0, stream>>>(part, nullptr, out, 1.f);
}

extern "C" void kernel_launch(void* const* d_in, const int* in_sizes, int n_in,
                              void* d_out, int out_size, void* d_ws, size_t ws_size,
                              hipStream_t stream)
{
  const float* u = (const float*)d_in[0];
  const float* W = (const float*)d_in[1];
  float* out = (float*)d_out;
  char* ws = (char*)d_ws;

  const size_t WBF_B = (size_t)N_IN * D_IN * J * 2;        // 64 MB
  const size_t UBF_B = (size_t)BATCH * N_IN * D_IN * 2;    // 4 MB
  const size_t SMALL = 2ull * BATCH * J * 4;               // v0+vs

  auto part_bytes = [](int nc) { return (size_t)nc * J * 64 * 4; };

  if (ws_size >= WBF_B + UBF_B + part_bytes(64) + SMALL) {
    short* Wbf = (short*)ws;
    short* ubf = (short*)(ws + WBF_B);
    float* part = (float*)(ws + WBF_B + UBF_B);
    float* v0 = part + (size_t)64 * J * 64;
    float* vs = v0 + BATCH * J;
    run_passes<0, 1, 32>(u, W, Wbf, ubf, part, v0, vs, out, stream);
  } else if (ws_size >= part_bytes(64) + SMALL) {
    float* part = (float*)ws;
    float* v0 = part + (size_t)64 * J * 64;
    float* vs = v0 + BATCH * J;
    run_passes<2, 2, 32>(u, W, nullptr, nullptr, part, v0, vs, out, stream);
  } else if (ws_size >= part_bytes(32) + SMALL) {
    float* part = (float*)ws;
    float* v0 = part + (size_t)32 * J * 64;
    float* vs = v0 + BATCH * J;
    run_passes<2, 2, 64>(u, W, nullptr, nullptr, part, v0, vs, out, stream);
  } else {
    float* part = (float*)ws;
    float* v0 = part + (size_t)16 * J * 64;
    float* vs = v0 + BATCH * J;
    run_passes<2, 2, 128>(u, W, nullptr, nullptr, part, v0, vs, out, stream);
  }
}